// Round 5
// baseline (309.045 us; speedup 1.0000x reference)
//
#include <hip/hip_runtime.h>
#include <hip/hip_bf16.h>
#include <stdint.h>

typedef __bf16 bf16x8 __attribute__((ext_vector_type(8)));
typedef float f32x4 __attribute__((ext_vector_type(4)));

constexpr int S = 1024, Bsz = 16, Hd = 1024;
constexpr int M = S * Bsz;   // 16384
constexpr int N = 3 * Hd;    // 3072
constexpr int K = 1024;
constexpr int BM = 128, BN = 128, BK = 32;
constexpr int NCH = 32, CS = S / NCH;  // 32 chunks x 32 steps
constexpr int BH = Bsz * Hd;           // 16384
constexpr int NX8 = 2097152;           // X bf16x8 chunks
constexpr int NW8 = 393216;            // W bf16x8 chunks

__device__ __forceinline__ float fast_sigmoid(float x) { return 1.0f / (1.0f + __expf(-x)); }
__device__ __forceinline__ float fast_tanh(float x) { return 2.0f / (1.0f + __expf(-2.0f * x)) - 1.0f; }

// async global->LDS 16B per lane; LDS dest is wave-uniform base + lane*16
__device__ __forceinline__ void gld_lds16(const __bf16* g, __bf16* l) {
  __builtin_amdgcn_global_load_lds(
      (const __attribute__((address_space(1))) void*)g,
      (__attribute__((address_space(3))) void*)l,
      16, 0, 0);
}

// ---- fused fp32 -> bf16 conversion for X and W, 8 elems/thread ----
__global__ void convert_all(const float* __restrict__ X, const float* __restrict__ W,
                            __bf16* __restrict__ Xb, __bf16* __restrict__ Wb) {
  int i = blockIdx.x * 256 + threadIdx.x;
  const float* s;
  __bf16* d;
  int idx;
  if (i < NX8) { s = X; d = Xb; idx = i; }
  else if (i < NX8 + NW8) { s = W; d = Wb; idx = i - NX8; }
  else return;
  const float4* s4 = (const float4*)s;
  float4 a = s4[2 * idx], b = s4[2 * idx + 1];
  bf16x8 v;
  v[0] = (__bf16)a.x; v[1] = (__bf16)a.y; v[2] = (__bf16)a.z; v[3] = (__bf16)a.w;
  v[4] = (__bf16)b.x; v[5] = (__bf16)b.y; v[6] = (__bf16)b.z; v[7] = (__bf16)b.w;
  *((bf16x8*)d + idx) = v;
}

// ---- bf16 MFMA GEMM (NT: C[m,n] = sum_k A[m,k]*W[n,k]) + bias + activation ----
// 128x128 tile, BK=32, 256 threads (4 waves, 2x2 of 64x64), 16x16x32 MFMA.
// At this structure's plateau (644 TF for K=1024): MfmaUtil ~27%, remaining
// stall is the barrier-drain (structural, per m99-m141). Conflicts 1.258e7
// are structural to wave64 ds_read_b128 (4 cyc/inst, swizzle-invariant).
__global__ __launch_bounds__(256) void gemm_act(const __bf16* __restrict__ A,
                                                const __bf16* __restrict__ Bw,
                                                const float* __restrict__ bias,
                                                __bf16* __restrict__ Y) {
  __shared__ __align__(16) __bf16 As[BM * BK];  // 8 KB, flat: elem = row*32 + col
  __shared__ __align__(16) __bf16 Bs[BN * BK];  // 8 KB
  const int t = threadIdx.x;
  const int lane = t & 63;
  const int wave = t >> 6;
  const int wm = wave >> 1, wn = wave & 1;
  const int tn = blockIdx.x % (N / BN);
  const int tm = blockIdx.x / (N / BN);
  const int m0 = tm * BM, n0 = tn * BN;
  const int lrow = lane & 15;
  const int quad = lane >> 4;

  const int srow = t >> 2;      // 0..63
  const int scw = t & 3;        // 16B sub-chunk within 32-elem row
  const __bf16* gA0 = A + (size_t)(m0 + srow) * K + scw * 8;
  const __bf16* gA1 = gA0 + (size_t)64 * K;
  const __bf16* gB0 = Bw + (size_t)(n0 + srow) * K + scw * 8;
  const __bf16* gB1 = gB0 + (size_t)64 * K;
  __bf16* lA0 = As + wave * 512;
  __bf16* lA1 = As + 2048 + wave * 512;
  __bf16* lB0 = Bs + wave * 512;
  __bf16* lB1 = Bs + 2048 + wave * 512;

  f32x4 acc[4][4] = {};

  for (int k0 = 0; k0 < K; k0 += BK) {
    __syncthreads();
    gld_lds16(gA0, lA0);
    gld_lds16(gA1, lA1);
    gld_lds16(gB0, lB0);
    gld_lds16(gB1, lB1);
    gA0 += BK; gA1 += BK; gB0 += BK; gB1 += BK;
    __syncthreads();

    bf16x8 af[4], bfr[4];
#pragma unroll
    for (int mi = 0; mi < 4; ++mi)
      af[mi] = *(const bf16x8*)(&As[(wm * 64 + mi * 16 + lrow) * BK + quad * 8]);
#pragma unroll
    for (int ni = 0; ni < 4; ++ni)
      bfr[ni] = *(const bf16x8*)(&Bs[(wn * 64 + ni * 16 + lrow) * BK + quad * 8]);
#pragma unroll
    for (int mi = 0; mi < 4; ++mi)
#pragma unroll
      for (int ni = 0; ni < 4; ++ni)
        acc[mi][ni] = __builtin_amdgcn_mfma_f32_16x16x32_bf16(af[mi], bfr[ni], acc[mi][ni], 0, 0, 0);
  }

  // epilogue: C/D layout col=lane&15, row=quad*4+reg (m89/m91-verified)
#pragma unroll
  for (int ni = 0; ni < 4; ++ni) {
    int col = n0 + wn * 64 + ni * 16 + lrow;
    float bv = bias[col];
    bool is_tanh = (col < Hd);
#pragma unroll
    for (int mi = 0; mi < 4; ++mi) {
#pragma unroll
      for (int r = 0; r < 4; ++r) {
        int m = m0 + wm * 64 + mi * 16 + quad * 4 + r;
        float y = acc[mi][ni][r] + bv;
        float v = is_tanh ? fast_tanh(y) : fast_sigmoid(y);
        Y[(size_t)m * N + col] = (__bf16)v;
      }
    }
  }
}

// ---- chunked affine scan, 8-wide over h: h_t = a*h + b, a=1-f, b=f*z ----
// thread -> (c, b, h0=8*h8): all Y loads are 16B bf16x8, fully coalesced.
// pass1: per-chunk composition (A,B): h_out = A*h_in + B
__global__ __launch_bounds__(256) void scan_pass1(const __bf16* __restrict__ Y,
                                                  float* __restrict__ Ac,
                                                  float* __restrict__ Bc) {
  int tid = blockIdx.x * 256 + threadIdx.x;  // 0..65535
  int c = tid >> 11;
  int bh8 = tid & 2047;
  int b = bh8 >> 7, h0 = (bh8 & 127) * 8;
  const size_t sstep = (size_t)Bsz * N;
  const __bf16* base = Y + (size_t)(c * CS) * sstep + (size_t)b * N + h0;
  float A[8], Bv[8];
#pragma unroll
  for (int l = 0; l < 8; ++l) { A[l] = 1.0f; Bv[l] = 0.0f; }
  for (int j0 = 0; j0 < CS; j0 += 8) {
    bf16x8 z[8], f[8];
#pragma unroll
    for (int j = 0; j < 8; ++j) {
      const __bf16* p = base + (size_t)(j0 + j) * sstep;
      z[j] = *(const bf16x8*)p;
      f[j] = *(const bf16x8*)(p + Hd);
    }
#pragma unroll
    for (int j = 0; j < 8; ++j)
#pragma unroll
      for (int l = 0; l < 8; ++l) {
        float ff = (float)f[j][l];
        float a = 1.0f - ff;
        Bv[l] = fmaf(a, Bv[l], ff * (float)z[j][l]);
        A[l] *= a;
      }
  }
  int ob = c * BH + b * Hd + h0;
#pragma unroll
  for (int l = 0; l < 8; ++l) { Ac[ob + l] = A[l]; Bc[ob + l] = Bv[l]; }
}

// pass2: chain chunk states; emit per-chunk h_in and C_last
__global__ __launch_bounds__(256) void scan_pass2(const float* __restrict__ Ac,
                                                  const float* __restrict__ Bc,
                                                  float* __restrict__ hin,
                                                  float* __restrict__ clast) {
  int bh = blockIdx.x * 256 + threadIdx.x;  // 0..BH-1
  float h = 0.0f;
#pragma unroll 4
  for (int c = 0; c < NCH; ++c) {
    hin[c * BH + bh] = h;
    h = fmaf(Ac[c * BH + bh], h, Bc[c * BH + bh]);
  }
  clast[bh] = h;
}

// pass3: replay chunk from known h_in, write Hout = o * h (2x float4 stores)
__global__ __launch_bounds__(256) void scan_pass3(const __bf16* __restrict__ Y,
                                                  const float* __restrict__ hin,
                                                  float* __restrict__ hout) {
  int tid = blockIdx.x * 256 + threadIdx.x;  // 0..65535
  int c = tid >> 11;
  int bh8 = tid & 2047;
  int b = bh8 >> 7, h0 = (bh8 & 127) * 8;
  const size_t sstep = (size_t)Bsz * N;
  const __bf16* base = Y + (size_t)(c * CS) * sstep + (size_t)b * N + h0;
  float* ob = hout + (size_t)(c * CS) * BH + (size_t)b * Hd + h0;
  float hp[8];
  int hb = c * BH + b * Hd + h0;
#pragma unroll
  for (int l = 0; l < 8; ++l) hp[l] = hin[hb + l];
  for (int j0 = 0; j0 < CS; j0 += 4) {
    bf16x8 z[4], f[4], o[4];
#pragma unroll
    for (int j = 0; j < 4; ++j) {
      const __bf16* p = base + (size_t)(j0 + j) * sstep;
      z[j] = *(const bf16x8*)p;
      f[j] = *(const bf16x8*)(p + Hd);
      o[j] = *(const bf16x8*)(p + 2 * Hd);
    }
#pragma unroll
    for (int j = 0; j < 4; ++j) {
      float out8[8];
#pragma unroll
      for (int l = 0; l < 8; ++l) {
        float ff = (float)f[j][l];
        hp[l] = fmaf(ff, (float)z[j][l] - hp[l], hp[l]);  // f*z + (1-f)*h
        out8[l] = (float)o[j][l] * hp[l];
      }
      float* op = ob + (size_t)(j0 + j) * BH;
      *(float4*)op = make_float4(out8[0], out8[1], out8[2], out8[3]);
      *(float4*)(op + 4) = make_float4(out8[4], out8[5], out8[6], out8[7]);
    }
  }
}

extern "C" void kernel_launch(void* const* d_in, const int* in_sizes, int n_in,
                              void* d_out, int out_size, void* d_ws, size_t ws_size,
                              hipStream_t stream) {
  const float* X = (const float*)d_in[0];    // [1024,16,1024]
  const float* W = (const float*)d_in[1];    // [3072,1024]
  const float* bias = (const float*)d_in[2]; // [3072]
  float* out = (float*)d_out;                // Hout (16777216) + C_last (16384)

  char* ws = (char*)d_ws;
  __bf16* Xb = (__bf16*)ws;                      // 33,554,432 B
  __bf16* Wb = (__bf16*)(ws + 33554432);         // 6,291,456 B
  __bf16* Yv = (__bf16*)(ws + 39845888);         // 100,663,296 B (bf16 Y)
  float* Ac = (float*)(ws + 39845888 + 100663296);
  float* Bc = Ac + NCH * BH;                     // 2 MB each
  float* hin = Bc + NCH * BH;

  convert_all<<<(NX8 + NW8) / 256, 256, 0, stream>>>(X, W, Xb, Wb);

  dim3 ggrid((M / BM) * (N / BN));  // 3072
  dim3 sgrid(NCH * BH / 8 / 256);   // 256
  gemm_act<<<ggrid, 256, 0, stream>>>(Xb, Wb, bias, Yv);
  scan_pass1<<<sgrid, 256, 0, stream>>>(Yv, Ac, Bc);
  scan_pass2<<<BH / 256, 256, 0, stream>>>(Ac, Bc, hin, out + 16777216);
  scan_pass3<<<sgrid, 256, 0, stream>>>(Yv, hin, out);
}